// Round 1
// baseline (144.947 us; speedup 1.0000x reference)
//
#include <hip/hip_runtime.h>
#include <hip/hip_bf16.h>

typedef short short8 __attribute__((ext_vector_type(8)));
typedef float f32x4 __attribute__((ext_vector_type(4)));
typedef unsigned short ushort_t;

// ---------- bf16 helpers (RNE) ----------
__device__ inline ushort_t f2bf(float f) {
    union { float f; unsigned u; } x; x.f = f;
    unsigned r = x.u + 0x7fffu + ((x.u >> 16) & 1u);
    return (ushort_t)(r >> 16);
}

// ---------- convert x (f32 -> bf16) ----------
__global__ __launch_bounds__(256) void conv_x_kernel(const float* __restrict__ xs,
                                                     const float* __restrict__ xd,
                                                     ushort_t* __restrict__ o0,
                                                     ushort_t* __restrict__ o1) {
    const float* in = blockIdx.y ? xd : xs;
    ushort_t* out = blockIdx.y ? o1 : o0;
    int i = blockIdx.x * 256 + threadIdx.x;
    float4 v = reinterpret_cast<const float4*>(in)[i];
    ushort4 o;
    o.x = f2bf(v.x); o.y = f2bf(v.y); o.z = f2bf(v.z); o.w = f2bf(v.w);
    reinterpret_cast<ushort4*>(out)[i] = o;
}

// ---------- transpose + convert weights: Wt[j][k] = bf16(W[k][j]), K=256 rows ----------
__global__ __launch_bounds__(256) void prep_w_kernel(const float* __restrict__ w0,
                                                     const float* __restrict__ w1,
                                                     const float* __restrict__ w2,
                                                     const float* __restrict__ w3,
                                                     ushort_t* __restrict__ t0,
                                                     ushort_t* __restrict__ t1,
                                                     ushort_t* __restrict__ t2,
                                                     ushort_t* __restrict__ t3) {
    int z = blockIdx.y;
    const float* W; ushort_t* T; int J;
    if (z == 0)      { W = w0; T = t0; J = 512; }
    else if (z == 1) { W = w1; T = t1; J = 512; }
    else if (z == 2) { W = w2; T = t2; J = 256; }
    else             { W = w3; T = t3; J = 256; }
    int idx = blockIdx.x * 256 + threadIdx.x;   // idx = j*256 + k
    if (idx >= J * 256) return;
    int k = idx & 255, j = idx >> 8;
    T[idx] = f2bf(W[k * J + j]);
}

// ---------- MFMA GEMM: C[M x N] = A[M x 256] @ Bt[N x 256]^T ----------
// A, Bt bf16 row-major (K contiguous). Block: 4 waves, each wave does 16 rows x 64 cols.
template<bool F32OUT>
__device__ inline void gemm_core(const ushort_t* __restrict__ A,
                                 const ushort_t* __restrict__ Bt,
                                 ushort_t* __restrict__ Cb,
                                 float* __restrict__ Cf,
                                 const float* __restrict__ bias, int N) {
    constexpr int K = 256;
    const int w = threadIdx.x >> 6;
    const int lane = threadIdx.x & 63;
    const int l16 = lane & 15, g = lane >> 4;
    const int m0 = blockIdx.x * 64 + w * 16;
    const int cb = blockIdx.y * 64;

    f32x4 acc[4] = {};
    const ushort_t* Ap = A + (size_t)(m0 + l16) * K + 8 * g;
    const ushort_t* Bp = Bt + (size_t)(cb + l16) * K + 8 * g;

    #pragma unroll
    for (int ks = 0; ks < K; ks += 32) {
        short8 a = *reinterpret_cast<const short8*>(Ap + ks);
        #pragma unroll
        for (int c = 0; c < 4; ++c) {
            short8 b = *reinterpret_cast<const short8*>(Bp + (size_t)c * 16 * K + ks);
            acc[c] = __builtin_amdgcn_mfma_f32_16x16x32_bf16(a, b, acc[c], 0, 0, 0);
        }
    }
    #pragma unroll
    for (int c = 0; c < 4; ++c) {
        int col = cb + c * 16 + l16;
        #pragma unroll
        for (int r = 0; r < 4; ++r) {
            int row = m0 + 4 * g + r;
            if (F32OUT) Cf[(size_t)row * N + col] = acc[c][r] + bias[col];
            else        Cb[(size_t)row * N + col] = f2bf(acc[c][r]);
        }
    }
}

__global__ __launch_bounds__(256) void gemm_in_kernel(const ushort_t* a0, const ushort_t* a1,
                                                      const ushort_t* b0, const ushort_t* b1,
                                                      ushort_t* c0, ushort_t* c1) {
    if (blockIdx.z == 0) gemm_core<false>(a0, b0, c0, nullptr, nullptr, 512);
    else                 gemm_core<false>(a1, b1, c1, nullptr, nullptr, 512);
}

__global__ __launch_bounds__(256) void gemm_out_kernel(const ushort_t* a0, const ushort_t* a1,
                                                       const ushort_t* b0, const ushort_t* b1,
                                                       float* c0, float* c1,
                                                       const float* bias0, const float* bias1) {
    if (blockIdx.z == 0) gemm_core<true>(a0, b0, nullptr, c0, bias0, 256);
    else                 gemm_core<true>(a1, b1, nullptr, c1, bias1, 256);
}

// ---------- Flash attention, both directions ----------
// rv layout: [B=2][N=2048][512] bf16, cols 0..255 = r (head h at h*32), 256..511 = v.
// dir 0: Q=r_sed, K=r_doa, V=v_doa -> o_sed.   dir 1: Q=r_doa, K=r_sed, V=v_sed -> o_doa.
// Each wave: 16 q-rows. S^T = mfma(Kfrag, Qfrag); lane (g,l16) holds S[q=l16][kv0+16t+4g+r].
// PV: O^T = mfma(V^Tfrag, Pfrag) with kv slot permutation folded into V addresses.
__global__ __launch_bounds__(256) void attn_kernel(const ushort_t* __restrict__ rv_sed,
                                                   const ushort_t* __restrict__ rv_doa,
                                                   ushort_t* __restrict__ o_sed,
                                                   ushort_t* __restrict__ o_doa) {
    const int dir = blockIdx.z;
    const ushort_t* rvQ  = dir ? rv_doa : rv_sed;
    const ushort_t* rvKV = dir ? rv_sed : rv_doa;
    ushort_t* O = dir ? o_doa : o_sed;

    const int b = blockIdx.y >> 3, h = blockIdx.y & 7;
    const int w = threadIdx.x >> 6;
    const int lane = threadIdx.x & 63;
    const int l16 = lane & 15, g = lane >> 4;
    const int q_row = blockIdx.x * 64 + w * 16 + l16;

    const ushort_t* qp = rvQ + (size_t)(b * 2048 + q_row) * 512 + h * 32 + 8 * g;
    const short8 qf = *reinterpret_cast<const short8*>(qp);

    const ushort_t* Kb = rvKV + (size_t)b * 2048 * 512 + h * 32;
    const ushort_t* Vb = Kb + 256;

    float m = -1e30f, l = 0.f;
    f32x4 acc0 = {}, acc1 = {};
    const float C2 = 0.17677669529663687f * 1.4426950408889634f;  // SCALE * log2(e)

    for (int kv0 = 0; kv0 < 2048; kv0 += 32) {
        const f32x4 z4 = {};
        short8 kf0 = *reinterpret_cast<const short8*>(Kb + (size_t)(kv0 + l16) * 512 + 8 * g);
        short8 kf1 = *reinterpret_cast<const short8*>(Kb + (size_t)(kv0 + 16 + l16) * 512 + 8 * g);
        f32x4 st0 = __builtin_amdgcn_mfma_f32_16x16x32_bf16(kf0, qf, z4, 0, 0, 0);
        f32x4 st1 = __builtin_amdgcn_mfma_f32_16x16x32_bf16(kf1, qf, z4, 0, 0, 0);

        float s[8];
        #pragma unroll
        for (int r = 0; r < 4; ++r) { s[r] = st0[r] * C2; s[4 + r] = st1[r] * C2; }
        float pmax = s[0];
        #pragma unroll
        for (int i = 1; i < 8; ++i) pmax = fmaxf(pmax, s[i]);
        pmax = fmaxf(pmax, __shfl_xor(pmax, 16));
        pmax = fmaxf(pmax, __shfl_xor(pmax, 32));
        float mn = fmaxf(m, pmax);
        float alpha = __builtin_amdgcn_exp2f(m - mn);

        float p[8], ps = 0.f;
        #pragma unroll
        for (int i = 0; i < 8; ++i) { p[i] = __builtin_amdgcn_exp2f(s[i] - mn); ps += p[i]; }
        ps += __shfl_xor(ps, 16);
        ps += __shfl_xor(ps, 32);
        l = l * alpha + ps;
        m = mn;
        #pragma unroll
        for (int r = 0; r < 4; ++r) { acc0[r] *= alpha; acc1[r] *= alpha; }

        short8 pf;
        #pragma unroll
        for (int i = 0; i < 8; ++i) pf[i] = (short)f2bf(p[i]);

        short8 vf0, vf1;
        #pragma unroll
        for (int e = 0; e < 8; ++e) {
            int kvr = kv0 + 16 * (e >> 2) + 4 * g + (e & 3);
            const ushort_t* vr = Vb + (size_t)kvr * 512;
            vf0[e] = (short)vr[l16];
            vf1[e] = (short)vr[l16 + 16];
        }
        acc0 = __builtin_amdgcn_mfma_f32_16x16x32_bf16(vf0, pf, acc0, 0, 0, 0);
        acc1 = __builtin_amdgcn_mfma_f32_16x16x32_bf16(vf1, pf, acc1, 0, 0, 0);
    }

    const float inv = 1.0f / l;
    ushort_t* orow = O + (size_t)(b * 2048 + q_row) * 256 + h * 32;
    ushort4 o0, o1;
    o0.x = f2bf(acc0[0] * inv); o0.y = f2bf(acc0[1] * inv);
    o0.z = f2bf(acc0[2] * inv); o0.w = f2bf(acc0[3] * inv);
    o1.x = f2bf(acc1[0] * inv); o1.y = f2bf(acc1[1] * inv);
    o1.z = f2bf(acc1[2] * inv); o1.w = f2bf(acc1[3] * inv);
    *reinterpret_cast<ushort4*>(orow + 4 * g) = o0;
    *reinterpret_cast<ushort4*>(orow + 16 + 4 * g) = o1;
}

// ---------- launch ----------
extern "C" void kernel_launch(void* const* d_in, const int* in_sizes, int n_in,
                              void* d_out, int out_size, void* d_ws, size_t ws_size,
                              hipStream_t stream) {
    const float* x_sed     = (const float*)d_in[0];
    const float* x_doa     = (const float*)d_in[1];
    const float* W_sed_in  = (const float*)d_in[2];
    const float* W_doa_in  = (const float*)d_in[3];
    const float* W_sed_out = (const float*)d_in[4];
    const float* b_sed_out = (const float*)d_in[5];
    const float* W_doa_out = (const float*)d_in[6];
    const float* b_doa_out = (const float*)d_in[7];
    float* out = (float*)d_out;

    ushort_t* ws = (ushort_t*)d_ws;
    ushort_t* xb_sed = ws;                           // 4096*256
    ushort_t* xb_doa = xb_sed + 1048576;             // 4096*256
    ushort_t* wt_si  = xb_doa + 1048576;             // 512*256
    ushort_t* wt_di  = wt_si  + 131072;              // 512*256
    ushort_t* wt_so  = wt_di  + 131072;              // 256*256
    ushort_t* wt_do  = wt_so  + 65536;               // 256*256
    ushort_t* rv_sed = wt_do  + 65536;               // 4096*512
    ushort_t* rv_doa = rv_sed + 2097152;             // 4096*512
    ushort_t* o_sed  = rv_doa + 2097152;             // 4096*256
    ushort_t* o_doa  = o_sed  + 1048576;             // 4096*256
    // total ~17.6 MB of ws

    conv_x_kernel<<<dim3(1024, 2), 256, 0, stream>>>(x_sed, x_doa, xb_sed, xb_doa);
    prep_w_kernel<<<dim3(512, 4), 256, 0, stream>>>(W_sed_in, W_doa_in, W_sed_out, W_doa_out,
                                                    wt_si, wt_di, wt_so, wt_do);
    gemm_in_kernel<<<dim3(64, 8, 2), 256, 0, stream>>>(xb_sed, xb_doa, wt_si, wt_di, rv_sed, rv_doa);
    attn_kernel<<<dim3(32, 16, 2), 256, 0, stream>>>(rv_sed, rv_doa, o_sed, o_doa);
    gemm_out_kernel<<<dim3(64, 4, 2), 256, 0, stream>>>(o_sed, o_doa, wt_so, wt_do,
                                                        out, out + 1048576, b_sed_out, b_doa_out);
}